// Round 5
// baseline (80509.119 us; speedup 1.0000x reference)
//
#include <hip/hip_runtime.h>
#include <math.h>

#define NB   512   // 2 blocks per CU (70 KB LDS each) — co-resident, 4 waves/SIMD
#define NT   512
#define Bsz  256
#define Ssz  256
#define Hsz  512
#define Osz  512
#define RWS  16    // batch rows per block
#define RSTRIDE 1032   // LDS row stride in floats (1024 + 8 pad)

#define AGENT __HIP_MEMORY_SCOPE_AGENT
#define RLX   __ATOMIC_RELAXED

// Dynamic LDS: RWS rows x RSTRIDE floats (66 KB), PLAIN ROW-MAJOR [emb(512)|h(512)].
// K-assignment per GEMM lane ks (0..31): k = i*128 + ks*4 (i = K-chunk index).
// -> LDS read per (i,r): 32 lanes x 16B contiguous (512 B) = 4-way bank floor.
// -> Weight read per i: 32 lanes x 16B contiguous (512 B) = perfectly coalesced,
//    reused across 16 rows from L1/L2. No slot transpose needed anywhere.
extern __shared__ float sx[];

// Stage the h-half of all RWS rows from global src (agent-scope loads bypass
// L1/L2 -> no stale data). 32 lanes/row; issue all 8 LLC loads, then write.
__device__ __forceinline__ void stage_h16(const float* src, int b0, int tid) {
  const int r = tid >> 5, pl = tid & 31;
  const float* rowp = src + (((size_t)(b0 + r)) << 9);
  unsigned long long v0[4], v1[4];
  #pragma unroll
  for (int m = 0; m < 4; ++m) {
    const int g = (m << 5) + pl;               // float4 group 0..127
    v0[m] = __hip_atomic_load((const unsigned long long*)(rowp + (g << 2)), RLX, AGENT);
    v1[m] = __hip_atomic_load((const unsigned long long*)(rowp + (g << 2) + 2), RLX, AGENT);
  }
  #pragma unroll
  for (int m = 0; m < 4; ++m) {
    const int g = (m << 5) + pl;
    float* d = &sx[r * RSTRIDE + 512 + (g << 2)];
    *(unsigned long long*)d       = v0[m];
    *(unsigned long long*)(d + 2) = v1[m];
  }
}

// Per-batch-group barrier: 16 groups of 32 blocks; groups are independent
// recurrences. Release: drain this wave's stores before the flag store.
__device__ __forceinline__ void group_barrier(unsigned* flags, unsigned& target,
                                              int gbase, int tid, int bid) {
  ++target;
  __builtin_amdgcn_s_waitcnt(0);
  __syncthreads();
  __atomic_signal_fence(__ATOMIC_SEQ_CST);
  if (tid == 0)
    __hip_atomic_store(&flags[bid], target, RLX, AGENT);
  if (tid < 32) {
    while (__hip_atomic_load(&flags[gbase + tid], RLX, AGENT) < target)
      __builtin_amdgcn_s_sleep(2);
  }
  __atomic_signal_fence(__ATOMIC_SEQ_CST);
  __syncthreads();
}

// Merged 2-column butterfly reduce over 32 K-lanes: lane 0 -> col0, lane 1 -> col1.
__device__ __forceinline__ float reduce2(float acc0, float acc1, int ks) {
  float u = (ks & 1) ? acc1 : acc0;
  float v = (ks & 1) ? acc0 : acc1;
  u += __shfl_xor(v, 1);
  u += __shfl_xor(u, 2);
  u += __shfl_xor(u, 4);
  u += __shfl_xor(u, 8);
  u += __shfl_xor(u, 16);
  return u;
}

// __launch_bounds__(NT, 2): empirically (r2-r4) caps at 128 VGPR -> 4 waves/SIMD
// -> 2 blocks/CU resident, which the grid barrier REQUIRES (512 blocks on 256 CUs).
__global__ __launch_bounds__(NT, 2) void gru_persistent(
    const int* __restrict__ x, const float* __restrict__ emb,
    const float* __restrict__ Wg, const float* __restrict__ bgp,
    const float* __restrict__ Wh, const float* __restrict__ bhp,
    const float* __restrict__ Wo, const float* __restrict__ bop,
    float* __restrict__ out, float* __restrict__ ws)
{
  const int tid  = threadIdx.x;
  const int bid  = blockIdx.x;
  const int bgrp = bid >> 5;          // 16 row-groups of RWS=16 batch rows
  const int jg   = bid & 31;          // 32 column-slice groups
  const int gbase = bgrp << 5;
  const int b0   = bgrp << 4;         // first batch row of this group
  const int jp   = tid >> 5;          // col-pair within slice (0..15)
  const int ks   = tid & 31;          // K lane
  const bool is_cand = (jg < 16);
  const int j0a = jg << 5;            // phase-A gate col base (0..1023)
  const int j0b = (jg & 15) << 5;     // phase-B col base (0..511)
  const int jc0 = jp << 1;            // first of this thread's 2 columns

  unsigned* flags = (unsigned*)ws;    // [512] barrier flags (memset 0)
  float* H0 = ws + 512;               // [256][512] h ping (memset 0 = h0)
  float* H1 = H0 + Bsz * Hsz;
  float* RH = H1 + Bsz * Hsz;
  float* ys = out + Bsz * Hsz;

  __shared__ float szv[RWS][32];
  __shared__ float shv[RWS][32];
  __shared__ int   sIdxN[RWS];

  // streamed-weight base pointers (per-lane K-chunk k = i*128 + ks*4)
  const float* wA0 = Wg + (size_t)(j0a + jc0) * 1024 + (ks << 2);
  const float* wA1 = wA0 + 1024;
  const float* wB0;
  const float* wB1;
  if (is_cand) {
    wB0 = Wh + (size_t)(j0b + jc0) * 1024 + (ks << 2);
    wB1 = wB0 + 1024;
  } else {
    wB0 = Wo + (size_t)(j0b + jc0) * 512 + (ks << 2);
    wB1 = wB0 + 512;
  }
  const float bA = bgp[j0a + jc0 + (ks & 1)];
  const float bB = is_cand ? bhp[j0b + jc0 + (ks & 1)] : bop[j0b + jc0 + (ks & 1)];

  // ---- xe prefetch: thread (pr,pl) owns 4 float4 of row pr's emb ----
  const int pr = tid >> 5, pl = tid & 31;
  float4 xv[4];

  if (tid < RWS) sIdxN[tid] = x[(b0 + tid) * Ssz];
  __syncthreads();
  {
    const float4* ep = (const float4*)(emb + (size_t)sIdxN[pr] * Hsz);
    #pragma unroll
    for (int m = 0; m < 4; ++m) xv[m] = ep[(m << 5) + pl];
  }

  unsigned target = 0;

  for (int t = 0; t < Ssz; ++t) {
    float* Hc = (t & 1) ? H1 : H0;
    float* Hn = (t & 1) ? H0 : H1;

    // ---- commit prefetched emb half (row-major: identical addressing both sides) ----
    #pragma unroll
    for (int m = 0; m < 4; ++m)
      *(float4*)&sx[pr * RSTRIDE + (((m << 5) + pl) << 2)] = xv[m];
    // ---- stage h half via LLC ----
    stage_h16(Hc, b0, tid);
    __syncthreads();

    // next step's token indices (consumed at the mid barrier)
    if (tid < RWS)
      sIdxN[tid] = x[(b0 + tid) * Ssz + ((t + 1 < Ssz) ? t + 1 : t)];

    // ---------------- Phase A: gates (K=1024, streamed Wg) ----------------
    {
      float acc0[RWS], acc1[RWS];
      #pragma unroll
      for (int r = 0; r < RWS; ++r) { acc0[r] = 0.f; acc1[r] = 0.f; }
      #pragma unroll
      for (int i = 0; i < 8; ++i) {
        const float4 w0 = *(const float4*)(wA0 + (i << 7));
        const float4 w1 = *(const float4*)(wA1 + (i << 7));
        #pragma unroll
        for (int r = 0; r < RWS; ++r) {
          const float4 xq = *(const float4*)&sx[r * RSTRIDE + (i << 7) + (ks << 2)];
          acc0[r] += w0.x * xq.x + w0.y * xq.y + w0.z * xq.z + w0.w * xq.w;
          acc1[r] += w1.x * xq.x + w1.y * xq.y + w1.z * xq.z + w1.w * xq.w;
        }
      }
      #pragma unroll
      for (int r = 0; r < RWS; ++r) {
        const float u = reduce2(acc0[r], acc1[r], ks);
        if (ks < 2) {
          const int jj = jc0 + ks;
          const float s = 1.f / (1.f + expf(-(u + bA)));
          if (is_cand) {
            szv[r][jj] = s;
            shv[r][jj] = sx[r * RSTRIDE + 512 + j0b + jj];
          } else {
            const int hj = j0a + jj - 512;
            const float hv = sx[r * RSTRIDE + 512 + hj];
            __hip_atomic_store(RH + (((size_t)(b0 + r)) << 9) + hj, s * hv, RLX, AGENT);
          }
        }
      }
    }

    // -------- mid barrier (per-bgrp) with xe-prefetch in the window --------
    {
      ++target;
      __builtin_amdgcn_s_waitcnt(0);
      __syncthreads();                 // sIdxN visible to all waves
      __atomic_signal_fence(__ATOMIC_SEQ_CST);
      if (tid == 0)
        __hip_atomic_store(&flags[bid], target, RLX, AGENT);
      {
        const float4* ep = (const float4*)(emb + (size_t)sIdxN[pr] * Hsz);
        #pragma unroll
        for (int m = 0; m < 4; ++m) xv[m] = ep[(m << 5) + pl];
      }
      if (tid < 32) {
        while (__hip_atomic_load(&flags[gbase + tid], RLX, AGENT) < target)
          __builtin_amdgcn_s_sleep(2);
      }
      __atomic_signal_fence(__ATOMIC_SEQ_CST);
      __syncthreads();
    }

    // ---------------- Phase B ----------------
    if (is_cand) {
      stage_h16(RH, b0, tid);          // overwrite h-half with r*h
      __syncthreads();
      float acc0[RWS], acc1[RWS];
      #pragma unroll
      for (int r = 0; r < RWS; ++r) { acc0[r] = 0.f; acc1[r] = 0.f; }
      #pragma unroll
      for (int i = 0; i < 8; ++i) {
        const float4 w0 = *(const float4*)(wB0 + (i << 7));
        const float4 w1 = *(const float4*)(wB1 + (i << 7));
        #pragma unroll
        for (int r = 0; r < RWS; ++r) {
          const float4 xq = *(const float4*)&sx[r * RSTRIDE + (i << 7) + (ks << 2)];
          acc0[r] += w0.x * xq.x + w0.y * xq.y + w0.z * xq.z + w0.w * xq.w;
          acc1[r] += w1.x * xq.x + w1.y * xq.y + w1.z * xq.z + w1.w * xq.w;
        }
      }
      #pragma unroll
      for (int r = 0; r < RWS; ++r) {
        const float u = reduce2(acc0[r], acc1[r], ks);
        if (ks < 2) {
          const int jj = jc0 + ks;
          const float cd = tanhf(u + bB);
          const float zv = szv[r][jj], hv = shv[r][jj];
          const float hn = (1.f - zv) * hv + zv * cd;
          __hip_atomic_store(Hn + (((size_t)(b0 + r)) << 9) + (j0b + jj), hn, RLX, AGENT);
          if (t == Ssz - 1) out[((b0 + r) << 9) + (j0b + jj)] = hn;
        }
      }
    } else if (t > 0) {
      float acc0[RWS], acc1[RWS];
      #pragma unroll
      for (int r = 0; r < RWS; ++r) { acc0[r] = 0.f; acc1[r] = 0.f; }
      #pragma unroll
      for (int i = 0; i < 4; ++i) {
        const float4 w0 = *(const float4*)(wB0 + (i << 7));
        const float4 w1 = *(const float4*)(wB1 + (i << 7));
        #pragma unroll
        for (int r = 0; r < RWS; ++r) {
          const float4 xq = *(const float4*)&sx[r * RSTRIDE + 512 + (i << 7) + (ks << 2)];
          acc0[r] += w0.x * xq.x + w0.y * xq.y + w0.z * xq.z + w0.w * xq.w;
          acc1[r] += w1.x * xq.x + w1.y * xq.y + w1.z * xq.z + w1.w * xq.w;
        }
      }
      #pragma unroll
      for (int r = 0; r < RWS; ++r) {
        const float u = reduce2(acc0[r], acc1[r], ks);
        if (ks < 2)
          ys[((size_t)(b0 + r) * Ssz + (t - 1)) * Osz + (j0b + jc0 + ks)] = u + bB;
      }
    }

    group_barrier(flags, target, gbase, tid, bid);
  }

  // ---- tail: y_{S-1} from h_S (Ssz even -> h_S in H0) ----
  if (!is_cand) {
    stage_h16(H0, b0, tid);
    __syncthreads();
    float acc0[RWS], acc1[RWS];
    #pragma unroll
    for (int r = 0; r < RWS; ++r) { acc0[r] = 0.f; acc1[r] = 0.f; }
    #pragma unroll
    for (int i = 0; i < 4; ++i) {
      const float4 w0 = *(const float4*)(wB0 + (i << 7));
      const float4 w1 = *(const float4*)(wB1 + (i << 7));
      #pragma unroll
      for (int r = 0; r < RWS; ++r) {
        const float4 xq = *(const float4*)&sx[r * RSTRIDE + 512 + (i << 7) + (ks << 2)];
        acc0[r] += w0.x * xq.x + w0.y * xq.y + w0.z * xq.z + w0.w * xq.w;
        acc1[r] += w1.x * xq.x + w1.y * xq.y + w1.z * xq.z + w1.w * xq.w;
      }
    }
    #pragma unroll
    for (int r = 0; r < RWS; ++r) {
      const float u = reduce2(acc0[r], acc1[r], ks);
      if (ks < 2)
        ys[((size_t)(b0 + r) * Ssz + (Ssz - 1)) * Osz + (j0b + jc0 + ks)] = u + bB;
    }
  }
}

extern "C" void kernel_launch(void* const* d_in, const int* in_sizes, int n_in,
                              void* d_out, int out_size, void* d_ws, size_t ws_size,
                              hipStream_t stream) {
  const int*   x   = (const int*)  d_in[0];
  const float* emb = (const float*)d_in[1];
  const float* Wg  = (const float*)d_in[2];
  const float* bg  = (const float*)d_in[3];
  const float* Wh  = (const float*)d_in[4];
  const float* bh  = (const float*)d_in[5];
  const float* Wo  = (const float*)d_in[6];
  const float* bo  = (const float*)d_in[7];
  float* out = (float*)d_out;
  float* ws  = (float*)d_ws;

  const int dynLds = RWS * RSTRIDE * 4;   // 66,048 B -> 2 blocks/CU
  hipFuncSetAttribute((const void*)gru_persistent,
                      hipFuncAttributeMaxDynamicSharedMemorySize, dynLds);

  // Zero barrier flags (512 u32) + H0 (= h0). ws re-poisoned every launch.
  hipMemsetAsync(d_ws, 0, (512 + Bsz * Hsz) * sizeof(float), stream);

  gru_persistent<<<NB, NT, dynLds, stream>>>(x, emb, Wg, bg, Wh, bh, Wo, bo, out, ws);
}

// Round 6
// 10501.788 us; speedup vs baseline: 7.6662x; 7.6662x over previous
//
#include <hip/hip_runtime.h>
#include <math.h>

#define NB   256   // one block per CU — co-resident (132 KB LDS forces 1/CU)
#define NT   512
#define Bsz  256
#define Ssz  256
#define Hsz  512
#define Osz  512
#define RSTRIDE 1032   // LDS row stride in floats (1024 + 8 pad: rotates banks/row)

#define AGENT __HIP_MEMORY_SCOPE_AGENT
#define RLX   __ATOMIC_RELAXED

// Dynamic LDS: 32 rows x RSTRIDE floats (132 KB), PLAIN ROW-MAJOR [emb(512)|h(512)].
// GEMM lane ks (0..31) reads float4 at k = i*128 + ks*4 (i = K-chunk):
// per (i,r) instr: 32 lanes x 16 B contiguous (512 B), lanes 32-63 broadcast
// -> conflict-free (R4's even/odd slot map was a structural 2-way conflict:
// 1.36e9 SQ_LDS_BANK_CONFLICT measured). Weights use the same k map:
// W + col*1024 + ks*4 + i*128 — per-wave coalesced 512 B, L1/L2-resident.
extern __shared__ float sx[];

// Stage the h-half of all 32 rows from global src (agent-scope loads bypass
// L1/L2 -> no stale data). 16 lanes/row x 8 float4; batched 2 rounds of 4:
// 8 outstanding LLC loads per round. Row-major dest: contiguous 256 B runs.
__device__ __forceinline__ void stage_h(const float* src, int b0, int tid) {
  const int r = tid >> 4, l = tid & 15;
  const float* rowp = src + (((size_t)(b0 + r)) << 9);
  #pragma unroll
  for (int hh = 0; hh < 2; ++hh) {
    unsigned long long v0[4], v1[4];
    #pragma unroll
    for (int m = 0; m < 4; ++m) {
      const int g = ((hh << 2) + m) * 16 + l;        // float4 idx 0..127
      v0[m] = __hip_atomic_load((const unsigned long long*)(rowp + (g << 2)), RLX, AGENT);
      v1[m] = __hip_atomic_load((const unsigned long long*)(rowp + (g << 2) + 2), RLX, AGENT);
    }
    #pragma unroll
    for (int m = 0; m < 4; ++m) {
      const int g = ((hh << 2) + m) * 16 + l;
      float* d = &sx[r * RSTRIDE + 512 + (g << 2)];
      *(unsigned long long*)d       = v0[m];
      *(unsigned long long*)(d + 2) = v1[m];
    }
  }
}

// Per-batch-group barrier: the 8 bgrps are fully independent recurrences,
// so sync only the 32 partner blocks. Release: drain this wave's stores
// (s_waitcnt 0) before the flag store.
__device__ __forceinline__ void group_barrier(unsigned* flags, unsigned& target,
                                              int gbase, int tid, int bid) {
  ++target;
  __builtin_amdgcn_s_waitcnt(0);
  __syncthreads();
  __atomic_signal_fence(__ATOMIC_SEQ_CST);
  if (tid == 0)
    __hip_atomic_store(&flags[bid], target, RLX, AGENT);
  if (tid < 32) {
    while (__hip_atomic_load(&flags[gbase + tid], RLX, AGENT) < target)
      __builtin_amdgcn_s_sleep(2);
  }
  __atomic_signal_fence(__ATOMIC_SEQ_CST);
  __syncthreads();
}

// Merged 2-column butterfly reduce over 32 K-lanes: lane 0 -> col0, lane 1 -> col1.
__device__ __forceinline__ float reduce2(float acc0, float acc1, int ks) {
  float u = (ks & 1) ? acc1 : acc0;
  float v = (ks & 1) ? acc0 : acc1;
  u += __shfl_xor(v, 1);
  u += __shfl_xor(u, 2);
  u += __shfl_xor(u, 4);
  u += __shfl_xor(u, 8);
  u += __shfl_xor(u, 16);
  return u;
}

__global__ __attribute__((amdgpu_flat_work_group_size(NT, NT),
                          amdgpu_waves_per_eu(2, 2)))
void gru_persistent(
    const int* __restrict__ x, const float* __restrict__ emb,
    const float* __restrict__ Wg, const float* __restrict__ bgp,
    const float* __restrict__ Wh, const float* __restrict__ bhp,
    const float* __restrict__ Wo, const float* __restrict__ bop,
    float* __restrict__ out, float* __restrict__ ws)
{
  const int tid  = threadIdx.x;
  const int bid  = blockIdx.x;
  const int bgrp = bid >> 5;          // 8 row-groups of 32 batch rows
  const int jg   = bid & 31;          // 32 column-slice groups
  const int gbase = bgrp << 5;
  const int b0   = bgrp << 5;
  const int jp   = tid >> 5;          // col-pair within slice (0..15)
  const int ks   = tid & 31;          // K lane (4 floats per i-chunk)
  const bool is_cand = (jg < 16);
  const int j0a = jg << 5;            // phase-A gate col base (0..1023)
  const int j0b = (jg & 15) << 5;     // phase-B col base (0..511)
  const int jc0 = jp << 1;            // first of this thread's 2 columns

  unsigned* flags = (unsigned*)ws;    // [256] barrier flags (memset 0)
  float* H0 = ws + 256;               // [256][512] h ping (memset 0 = h0)
  float* H1 = H0 + Bsz * Hsz;
  float* RH = H1 + Bsz * Hsz;
  float* ys = out + Bsz * Hsz;

  __shared__ float szv[32][32];
  __shared__ float shv[32][32];
  __shared__ int   sIdxN[32];         // next step's token index per row

  // ---- persistent register weights: interleaved K map k = i*128 + ks*4 ----
  float4 wa0[8], wa1[8];
  {
    const float* p0 = Wg + (size_t)(j0a + jc0) * 1024 + (ks << 2);
    const float* p1 = p0 + 1024;
    #pragma unroll
    for (int i = 0; i < 8; ++i) {
      wa0[i] = *(const float4*)(p0 + (i << 7));
      wa1[i] = *(const float4*)(p1 + (i << 7));
    }
  }
  float4 wb0[8], wb1[8];
  if (is_cand) {
    const float* p0 = Wh + (size_t)(j0b + jc0) * 1024 + (ks << 2);
    const float* p1 = p0 + 1024;
    #pragma unroll
    for (int i = 0; i < 8; ++i) {
      wb0[i] = *(const float4*)(p0 + (i << 7));
      wb1[i] = *(const float4*)(p1 + (i << 7));
    }
  } else {
    const float* p0 = Wo + (size_t)(j0b + jc0) * 512 + (ks << 2);
    const float* p1 = p0 + 512;
    #pragma unroll
    for (int i = 0; i < 4; ++i) {
      wb0[i] = *(const float4*)(p0 + (i << 7));
      wb1[i] = *(const float4*)(p1 + (i << 7));
    }
    #pragma unroll
    for (int i = 4; i < 8; ++i) {
      wb0[i] = make_float4(0.f, 0.f, 0.f, 0.f);
      wb1[i] = make_float4(0.f, 0.f, 0.f, 0.f);
    }
  }
  const float bA = bgp[j0a + jc0 + (ks & 1)];
  const float bB = is_cand ? bhp[j0b + jc0 + (ks & 1)] : bop[j0b + jc0 + (ks & 1)];

  // ---- xe prefetch: thread (pr,pl) owns 8 float4 of row pr's emb ----
  const int pr = tid >> 4, pl = tid & 15;
  float4 xv[8];

  if (tid < 32) sIdxN[tid] = x[(b0 + tid) * Ssz];
  __syncthreads();
  {
    const float4* ep = (const float4*)(emb + (size_t)sIdxN[pr] * Hsz);
    #pragma unroll
    for (int m = 0; m < 8; ++m) xv[m] = ep[(m << 4) + pl];
  }

  unsigned target = 0;

  for (int t = 0; t < Ssz; ++t) {
    float* Hc = (t & 1) ? H1 : H0;
    float* Hn = (t & 1) ? H0 : H1;

    // ---- commit prefetched emb half (row-major, contiguous 256 B runs) ----
    #pragma unroll
    for (int m = 0; m < 8; ++m)
      *(float4*)&sx[pr * RSTRIDE + (((m << 4) + pl) << 2)] = xv[m];
    // ---- stage h half via LLC ----
    stage_h(Hc, b0, tid);
    __syncthreads();

    // next step's token indices (consumed at the mid barrier)
    if (tid < 32)
      sIdxN[tid] = x[(b0 + tid) * Ssz + ((t + 1 < Ssz) ? t + 1 : t)];

    // ---------------- Phase A: gates (K=1024, 2 cols/thread) ----------------
    {
      const int bx = ks << 2;
      #pragma unroll 2
      for (int r = 0; r < 32; ++r) {
        const float* xp = &sx[r * RSTRIDE + bx];
        float p00 = 0.f, p01 = 0.f, p02 = 0.f, p03 = 0.f;
        float p10 = 0.f, p11 = 0.f, p12 = 0.f, p13 = 0.f;
        #pragma unroll
        for (int i = 0; i < 8; ++i) {
          const float4 xq = *(const float4*)(xp + (i << 7));
          p00 += wa0[i].x * xq.x; p01 += wa0[i].y * xq.y;
          p02 += wa0[i].z * xq.z; p03 += wa0[i].w * xq.w;
          p10 += wa1[i].x * xq.x; p11 += wa1[i].y * xq.y;
          p12 += wa1[i].z * xq.z; p13 += wa1[i].w * xq.w;
        }
        const float u = reduce2((p00 + p01) + (p02 + p03),
                                (p10 + p11) + (p12 + p13), ks);
        if (ks < 2) {
          const int jj = jc0 + ks;
          const float s = 1.f / (1.f + expf(-(u + bA)));
          if (is_cand) {
            szv[r][jj] = s;
            shv[r][jj] = sx[r * RSTRIDE + 512 + j0b + jj];
          } else {
            const int hj = j0a + jj - 512;
            const float hv = sx[r * RSTRIDE + 512 + hj];
            __hip_atomic_store(RH + (((size_t)(b0 + r)) << 9) + hj, s * hv, RLX, AGENT);
          }
        }
      }
    }

    // -------- mid barrier (per-bgrp) with xe-prefetch in the window --------
    {
      ++target;
      __builtin_amdgcn_s_waitcnt(0);
      __syncthreads();                 // sIdxN visible to all waves
      __atomic_signal_fence(__ATOMIC_SEQ_CST);
      if (tid == 0)
        __hip_atomic_store(&flags[bid], target, RLX, AGENT);
      {
        const float4* ep = (const float4*)(emb + (size_t)sIdxN[pr] * Hsz);
        #pragma unroll
        for (int m = 0; m < 8; ++m) xv[m] = ep[(m << 4) + pl];
      }
      if (tid < 32) {
        while (__hip_atomic_load(&flags[gbase + tid], RLX, AGENT) < target)
          __builtin_amdgcn_s_sleep(2);
      }
      __atomic_signal_fence(__ATOMIC_SEQ_CST);
      __syncthreads();
    }

    // ---------------- Phase B ----------------
    if (is_cand) {
      stage_h(RH, b0, tid);            // overwrite h-half with r*h
      __syncthreads();
      const int bx = ks << 2;
      #pragma unroll 2
      for (int r = 0; r < 32; ++r) {
        const float* xp = &sx[r * RSTRIDE + bx];
        float p00 = 0.f, p01 = 0.f, p02 = 0.f, p03 = 0.f;
        float p10 = 0.f, p11 = 0.f, p12 = 0.f, p13 = 0.f;
        #pragma unroll
        for (int i = 0; i < 8; ++i) {
          const float4 xq = *(const float4*)(xp + (i << 7));
          p00 += wb0[i].x * xq.x; p01 += wb0[i].y * xq.y;
          p02 += wb0[i].z * xq.z; p03 += wb0[i].w * xq.w;
          p10 += wb1[i].x * xq.x; p11 += wb1[i].y * xq.y;
          p12 += wb1[i].z * xq.z; p13 += wb1[i].w * xq.w;
        }
        const float u = reduce2((p00 + p01) + (p02 + p03),
                                (p10 + p11) + (p12 + p13), ks);
        if (ks < 2) {
          const int jj = jc0 + ks;
          const float cd = tanhf(u + bB);
          const float zv = szv[r][jj], hv = shv[r][jj];
          const float hn = (1.f - zv) * hv + zv * cd;
          __hip_atomic_store(Hn + (((size_t)(b0 + r)) << 9) + (j0b + jj), hn, RLX, AGENT);
          if (t == Ssz - 1) out[((b0 + r) << 9) + (j0b + jj)] = hn;
        }
      }
    } else if (t > 0) {
      const int bx = 512 + (ks << 2);
      #pragma unroll 2
      for (int r = 0; r < 32; ++r) {
        const float* xp = &sx[r * RSTRIDE + bx];
        float p00 = 0.f, p01 = 0.f, p02 = 0.f, p03 = 0.f;
        float p10 = 0.f, p11 = 0.f, p12 = 0.f, p13 = 0.f;
        #pragma unroll
        for (int i = 0; i < 4; ++i) {
          const float4 xq = *(const float4*)(xp + (i << 7));
          p00 += wb0[i].x * xq.x; p01 += wb0[i].y * xq.y;
          p02 += wb0[i].z * xq.z; p03 += wb0[i].w * xq.w;
          p10 += wb1[i].x * xq.x; p11 += wb1[i].y * xq.y;
          p12 += wb1[i].z * xq.z; p13 += wb1[i].w * xq.w;
        }
        const float u = reduce2((p00 + p01) + (p02 + p03),
                                (p10 + p11) + (p12 + p13), ks);
        if (ks < 2)
          ys[((size_t)(b0 + r) * Ssz + (t - 1)) * Osz + (j0b + jc0 + ks)] = u + bB;
      }
    }

    group_barrier(flags, target, gbase, tid, bid);
  }

  // ---- tail: y_{S-1} from h_S (Ssz even -> h_S in H0) ----
  if (!is_cand) {
    stage_h(H0, b0, tid);
    __syncthreads();
    const int bx = 512 + (ks << 2);
    #pragma unroll 2
    for (int r = 0; r < 32; ++r) {
      const float* xp = &sx[r * RSTRIDE + bx];
      float p00 = 0.f, p01 = 0.f, p02 = 0.f, p03 = 0.f;
      float p10 = 0.f, p11 = 0.f, p12 = 0.f, p13 = 0.f;
      #pragma unroll
      for (int i = 0; i < 4; ++i) {
        const float4 xq = *(const float4*)(xp + (i << 7));
        p00 += wb0[i].x * xq.x; p01 += wb0[i].y * xq.y;
        p02 += wb0[i].z * xq.z; p03 += wb0[i].w * xq.w;
        p10 += wb1[i].x * xq.x; p11 += wb1[i].y * xq.y;
        p12 += wb1[i].z * xq.z; p13 += wb1[i].w * xq.w;
      }
      const float u = reduce2((p00 + p01) + (p02 + p03),
                              (p10 + p11) + (p12 + p13), ks);
      if (ks < 2)
        ys[((size_t)(b0 + r) * Ssz + (Ssz - 1)) * Osz + (j0b + jc0 + ks)] = u + bB;
    }
  }
}

extern "C" void kernel_launch(void* const* d_in, const int* in_sizes, int n_in,
                              void* d_out, int out_size, void* d_ws, size_t ws_size,
                              hipStream_t stream) {
  const int*   x   = (const int*)  d_in[0];
  const float* emb = (const float*)d_in[1];
  const float* Wg  = (const float*)d_in[2];
  const float* bg  = (const float*)d_in[3];
  const float* Wh  = (const float*)d_in[4];
  const float* bh  = (const float*)d_in[5];
  const float* Wo  = (const float*)d_in[6];
  const float* bo  = (const float*)d_in[7];
  float* out = (float*)d_out;
  float* ws  = (float*)d_ws;

  const int dynLds = 32 * RSTRIDE * 4;   // 132,096 B -> 1 block/CU
  hipFuncSetAttribute((const void*)gru_persistent,
                      hipFuncAttributeMaxDynamicSharedMemorySize, dynLds);

  // Zero barrier flags (256 u32) + H0 (= h0). ws re-poisoned every launch.
  hipMemsetAsync(d_ws, 0, (256 + Bsz * Hsz) * sizeof(float), stream);

  gru_persistent<<<NB, NT, dynLds, stream>>>(x, emb, Wg, bg, Wh, bh, Wo, bo, out, ws);
}